// Round 2
// baseline (58976.025 us; speedup 1.0000x reference)
//
#include <hip/hip_runtime.h>
#include <math.h>

// Problem dims (fixed by reference)
constexpr int T  = 512;
constexpr int BB = 64;    // batch
constexpr int II = 256;   // input
constexpr int HH = 512;   // hidden

// d_out layout (floats): out[B,T,H] | s[2,B,H] | h[2,B,H] | c[2,B,H]
constexpr int SOFF = BB * T * HH;          // 16777216
constexpr int HOFF = SOFF + 2 * BB * HH;   // +65536
constexpr int COFF = HOFF + 2 * BB * HH;

// Workspace layout (float offsets). Total ~53.6 MB.
constexpr int WS_XT    = 0;                        // [T][II][BB]
constexpr int WS_WX0P  = 8388608;                  // [512 j][256 k] float4
constexpr int WS_WH0P  = 8912896;                  // [512 j][512 k] float4
constexpr int WS_WX1P  = 9961472;
constexpr int WS_WH1P  = 11010048;
constexpr int WS_BH0P  = 12058624;                 // [512] float4
constexpr int WS_BH1P  = 12060672;
constexpr int WS_U0    = 12062720;                 // ring4 [j][b] float4
constexpr int WS_U1    = 12587008;                 // ring4
constexpr int WS_H0    = 13111296;                 // dbuf2 [k][b] float
constexpr int WS_H1    = 13176832;                 // dbuf2
constexpr int WS_S0    = 13242368;                 // ring4 [k][b] float
constexpr int WS_BAR   = 13373440;                 // barrier counters (1024 floats)

// ---------------- setup kernels ----------------

// xT[t][k][b] = x[b][t][k]
__global__ void transpose_x(const float* __restrict__ x, float* __restrict__ xT) {
  __shared__ float tile[64][65];
  const int t  = blockIdx.x >> 2;
  const int k0 = (blockIdx.x & 3) * 64;
  const int tid = threadIdx.x;
#pragma unroll
  for (int r = 0; r < 16; ++r) {
    int idx = r * 256 + tid;
    int bb = idx >> 6, kk = idx & 63;
    tile[bb][kk] = x[bb * (T * II) + t * II + k0 + kk];
  }
  __syncthreads();
#pragma unroll
  for (int r = 0; r < 16; ++r) {
    int idx = r * 256 + tid;
    int kk = idx >> 6, bb = idx & 63;
    xT[t * (II * BB) + (k0 + kk) * BB + bb] = tile[bb][kk];
  }
}

// Wp[j][k] = (W[k][j], W[k][H+j], W[k][2H+j], W[k][3H+j]);  W is [K][4H]
__global__ void pack_w(const float* __restrict__ W, float4* __restrict__ Wp, int K) {
  const int i = blockIdx.x * blockDim.x + threadIdx.x;  // [0, K*512)
  const int j = i & 511;
  const int k = i >> 9;
  float4 v;
  v.x = W[k * 2048 + j];
  v.y = W[k * 2048 + 512 + j];
  v.z = W[k * 2048 + 1024 + j];
  v.w = W[k * 2048 + 1536 + j];
  Wp[j * K + k] = v;
}

__global__ void pack_bias(const float* __restrict__ bh0, const float* __restrict__ bh1,
                          float* __restrict__ bh0p, float* __restrict__ bh1p) {
  const int i = blockIdx.x * blockDim.x + threadIdx.x;  // 4096
  if (i < 2048) {
    bh0p[i] = bh0[(i & 3) * 512 + (i >> 2)];
  } else {
    int q = i - 2048;
    bh1p[q] = bh1[(q & 3) * 512 + (q >> 2)];
  }
}

// ---------------- device helpers ----------------

__device__ __forceinline__ float sigf(float x) { return 1.0f / (1.0f + __expf(-x)); }
__device__ __forceinline__ float tanh_fast(float x) {
  // tanh(x) = 1 - 2/(1+e^{2x});  saturates correctly for |x| large
  return 1.0f - 2.0f / (1.0f + __expf(2.0f * x));
}

// Partial 4-column dot: acc[j] += sum_{k in [k0,k0+KC)} sv[k*64] * wj[k]
template <int KC>
__device__ __forceinline__ void dot4x4(const float* __restrict__ sv,
                                       const float4* __restrict__ w0,
                                       const float4* __restrict__ w1,
                                       const float4* __restrict__ w2,
                                       const float4* __restrict__ w3,
                                       int k0,
                                       float4& A0, float4& A1, float4& A2, float4& A3) {
  float4 a0 = {0, 0, 0, 0}, a1 = {0, 0, 0, 0}, a2 = {0, 0, 0, 0}, a3 = {0, 0, 0, 0};
#pragma unroll 4
  for (int k = k0; k < k0 + KC; ++k) {
    const float v = sv[k * 64];
    float4 w = w0[k];
    a0.x = fmaf(v, w.x, a0.x); a0.y = fmaf(v, w.y, a0.y);
    a0.z = fmaf(v, w.z, a0.z); a0.w = fmaf(v, w.w, a0.w);
    w = w1[k];
    a1.x = fmaf(v, w.x, a1.x); a1.y = fmaf(v, w.y, a1.y);
    a1.z = fmaf(v, w.z, a1.z); a1.w = fmaf(v, w.w, a1.w);
    w = w2[k];
    a2.x = fmaf(v, w.x, a2.x); a2.y = fmaf(v, w.y, a2.y);
    a2.z = fmaf(v, w.z, a2.z); a2.w = fmaf(v, w.w, a2.w);
    w = w3[k];
    a3.x = fmaf(v, w.x, a3.x); a3.y = fmaf(v, w.y, a3.y);
    a3.z = fmaf(v, w.z, a3.z); a3.w = fmaf(v, w.w, a3.w);
  }
  A0 = a0; A1 = a1; A2 = a2; A3 = a3;
}

// Hierarchical grid barrier: 8 group counters -> 1 global counter.
// All counters monotonic; zeroed by hipMemsetAsync each launch.
__device__ __forceinline__ void gbar(unsigned* __restrict__ bar, int wg, unsigned it) {
  __syncthreads();
  if (threadIdx.x == 0) {
    __threadfence();  // release: make this block's writes visible device-wide
    unsigned* c1 = bar + ((wg >> 6) << 5);  // 8 counters, 128B apart
    unsigned* c2 = bar + 512;
    unsigned old = __hip_atomic_fetch_add(c1, 1u, __ATOMIC_ACQ_REL, __HIP_MEMORY_SCOPE_AGENT);
    if (old == it * 64u + 63u) {
      __hip_atomic_fetch_add(c2, 1u, __ATOMIC_ACQ_REL, __HIP_MEMORY_SCOPE_AGENT);
    }
    const unsigned tgt = (it + 1u) * 8u;
    while (__hip_atomic_load(c2, __ATOMIC_ACQUIRE, __HIP_MEMORY_SCOPE_AGENT) < tgt) {
      __builtin_amdgcn_s_sleep(4);
    }
    __threadfence();  // acquire side: invalidate caches before consuming
  }
  __syncthreads();
}

// ---------------- main persistent kernel ----------------
// 512 blocks x 256 threads, 2 blocks/CU. Thread = (q = tid>>6, b = tid&63).
// Block owns 4 gate-columns j = jb..jb+3; wave q computes the k-chunk partial
// for all 4 j's; LDS exchange; thread (q,b) finalizes column j = jb+q.
// Stages: A = layer0 recurrence (t = tt-1), B = layer1 recurrence (t = tt-3),
//         D = x@Wx0 (t = tt), C = s0@Wx1 (t = tt-2). One grid barrier per iter.
__global__ __launch_bounds__(256, 2) void aslstm_main(
    const float* __restrict__ xT,
    const float4* __restrict__ Wx0p, const float4* __restrict__ Wh0p,
    const float4* __restrict__ Wx1p, const float4* __restrict__ Wh1p,
    const float4* __restrict__ bh0p, const float4* __restrict__ bh1p,
    float4* __restrict__ u0ring, float4* __restrict__ u1ring,
    float* __restrict__ h0buf, float* __restrict__ h1buf,
    float* __restrict__ s0ring, float* __restrict__ out,
    unsigned* __restrict__ bar) {
  const int wg  = blockIdx.x;
  const int tid = threadIdx.x;
  const int q   = tid >> 6;
  const int b   = tid & 63;

  // Interleave stages so (if dispatch is round-robin) each CU pairs a heavy
  // block (A/B) with a lighter one (D/C).
  int stage, w;
  if (wg < 256) { stage = (wg & 1) ? 3 : 1; w = wg >> 1; }   // 1 = A, 3 = B
  else { int u = wg - 256; stage = (u & 1) ? 2 : 0; w = u >> 1; }  // 0 = D, 2 = C
  const int jb = w * 4;
  const int j  = jb + q;   // column this thread finalizes

  __shared__ float4 part[4][4][64];  // [q][jo][b] 16 KB

  float c_reg = 0.0f;  // c0 (stage A) or c1 (stage B), per (j,b)

  for (int tt = 0; tt < T + 3; ++tt) {
    if (stage == 0) {
      // D: u0[t] = bh0 + x[t] @ Wx0
      const int t = tt;
      if (t < T) {
        const float* sv = xT + t * (II * BB) + b;
        float4 a0, a1, a2, a3;
        dot4x4<II / 4>(sv, Wx0p + (jb + 0) * II, Wx0p + (jb + 1) * II,
                       Wx0p + (jb + 2) * II, Wx0p + (jb + 3) * II, q * (II / 4),
                       a0, a1, a2, a3);
        part[q][0][b] = a0; part[q][1][b] = a1; part[q][2][b] = a2; part[q][3][b] = a3;
        __syncthreads();
        float4 p0 = part[0][q][b], p1 = part[1][q][b], p2 = part[2][q][b], p3 = part[3][q][b];
        float4 bia = bh0p[j];
        float4 acc;
        acc.x = p0.x + p1.x + p2.x + p3.x + bia.x;
        acc.y = p0.y + p1.y + p2.y + p3.y + bia.y;
        acc.z = p0.z + p1.z + p2.z + p3.z + bia.z;
        acc.w = p0.w + p1.w + p2.w + p3.w + bia.w;
        u0ring[(t & 3) * (HH * BB) + j * BB + b] = acc;
      }
    } else if (stage == 1) {
      // A: layer-0 recurrence, gates, spike
      const int t = tt - 1;
      if (t >= 0 && t < T) {
        const float* sv = h0buf + ((t + 1) & 1) * (HH * BB) + b;  // h0[t-1]
        float4 a0, a1, a2, a3;
        dot4x4<HH / 4>(sv, Wh0p + (jb + 0) * HH, Wh0p + (jb + 1) * HH,
                       Wh0p + (jb + 2) * HH, Wh0p + (jb + 3) * HH, q * (HH / 4),
                       a0, a1, a2, a3);
        part[q][0][b] = a0; part[q][1][b] = a1; part[q][2][b] = a2; part[q][3][b] = a3;
        __syncthreads();
        float4 p0 = part[0][q][b], p1 = part[1][q][b], p2 = part[2][q][b], p3 = part[3][q][b];
        float4 u0 = u0ring[(t & 3) * (HH * BB) + j * BB + b];
        const float pi = p0.x + p1.x + p2.x + p3.x + u0.x;
        const float pf = p0.y + p1.y + p2.y + p3.y + u0.y;
        const float pg = p0.z + p1.z + p2.z + p3.z + u0.z;
        const float po = p0.w + p1.w + p2.w + p3.w + u0.w;
        const float cn  = sigf(pf) * c_reg + sigf(pi) * tanh_fast(pg);
        const float mem = sigf(po) * tanh_fast(cn);  // s*0.2*(1-s) == 0 for s in {0,1}
        const float sn  = (mem > 0.5f) ? 1.0f : 0.0f;
        c_reg = cn;
        h0buf[(t & 1) * (HH * BB) + j * 64 + b]  = mem;
        s0ring[(t & 3) * (HH * BB) + j * 64 + b] = sn;
        if (t == T - 1) {
          out[SOFF + b * HH + j] = sn;
          out[HOFF + b * HH + j] = mem;
          out[COFF + b * HH + j] = cn;
        }
      }
    } else if (stage == 2) {
      // C: u1[t] = bh1 + s0[t] @ Wx1
      const int t = tt - 2;
      if (t >= 0 && t < T) {
        const float* sv = s0ring + (t & 3) * (HH * BB) + b;
        float4 a0, a1, a2, a3;
        dot4x4<HH / 4>(sv, Wx1p + (jb + 0) * HH, Wx1p + (jb + 1) * HH,
                       Wx1p + (jb + 2) * HH, Wx1p + (jb + 3) * HH, q * (HH / 4),
                       a0, a1, a2, a3);
        part[q][0][b] = a0; part[q][1][b] = a1; part[q][2][b] = a2; part[q][3][b] = a3;
        __syncthreads();
        float4 p0 = part[0][q][b], p1 = part[1][q][b], p2 = part[2][q][b], p3 = part[3][q][b];
        float4 bia = bh1p[j];
        float4 acc;
        acc.x = p0.x + p1.x + p2.x + p3.x + bia.x;
        acc.y = p0.y + p1.y + p2.y + p3.y + bia.y;
        acc.z = p0.z + p1.z + p2.z + p3.z + bia.z;
        acc.w = p0.w + p1.w + p2.w + p3.w + bia.w;
        u1ring[(t & 3) * (HH * BB) + j * BB + b] = acc;
      }
    } else {
      // B: layer-1 recurrence, gates, leaky output neuron
      const int t = tt - 3;
      if (t >= 0 && t < T) {
        const float* sv = h1buf + ((t + 1) & 1) * (HH * BB) + b;  // h1[t-1]
        float4 a0, a1, a2, a3;
        dot4x4<HH / 4>(sv, Wh1p + (jb + 0) * HH, Wh1p + (jb + 1) * HH,
                       Wh1p + (jb + 2) * HH, Wh1p + (jb + 3) * HH, q * (HH / 4),
                       a0, a1, a2, a3);
        part[q][0][b] = a0; part[q][1][b] = a1; part[q][2][b] = a2; part[q][3][b] = a3;
        __syncthreads();
        float4 p0 = part[0][q][b], p1 = part[1][q][b], p2 = part[2][q][b], p3 = part[3][q][b];
        float4 u1 = u1ring[(t & 3) * (HH * BB) + j * BB + b];
        const float pi = p0.x + p1.x + p2.x + p3.x + u1.x;
        const float pf = p0.y + p1.y + p2.y + p3.y + u1.y;
        const float pg = p0.z + p1.z + p2.z + p3.z + u1.z;
        const float po = p0.w + p1.w + p2.w + p3.w + u1.w;
        const float cn = sigf(pf) * c_reg + sigf(pi) * tanh_fast(pg);
        const float hn = sigf(po) * tanh_fast(cn);
        const float sp = s0ring[(t & 3) * (HH * BB) + j * 64 + b];
        const float h1n = hn * 0.2f + sp;
        c_reg = cn;
        h1buf[(t & 1) * (HH * BB) + j * 64 + b] = h1n;
        out[b * (T * HH) + t * HH + j] = h1n;
        if (t == T - 1) {
          out[HOFF + HH * BB + b * HH + j] = h1n;
          out[COFF + HH * BB + b * HH + j] = cn;
        }
      }
    }
    gbar(bar, wg, (unsigned)tt);
  }
}

// ---------------- launch ----------------

extern "C" void kernel_launch(void* const* d_in, const int* in_sizes, int n_in,
                              void* d_out, int out_size, void* d_ws, size_t ws_size,
                              hipStream_t stream) {
  const float* x   = (const float*)d_in[0];
  const float* Wx0 = (const float*)d_in[1];
  const float* Wh0 = (const float*)d_in[2];
  const float* bh0 = (const float*)d_in[3];
  const float* Wx1 = (const float*)d_in[4];
  const float* Wh1 = (const float*)d_in[5];
  const float* bh1 = (const float*)d_in[6];
  float* out = (float*)d_out;
  float* ws  = (float*)d_ws;

  float*    xT    = ws + WS_XT;
  float4*   Wx0p  = (float4*)(ws + WS_WX0P);
  float4*   Wh0p  = (float4*)(ws + WS_WH0P);
  float4*   Wx1p  = (float4*)(ws + WS_WX1P);
  float4*   Wh1p  = (float4*)(ws + WS_WH1P);
  float*    bh0pf = ws + WS_BH0P;
  float*    bh1pf = ws + WS_BH1P;
  float4*   bh0p  = (float4*)bh0pf;
  float4*   bh1p  = (float4*)bh1pf;
  float4*   u0r   = (float4*)(ws + WS_U0);
  float4*   u1r   = (float4*)(ws + WS_U1);
  float*    h0buf = ws + WS_H0;
  float*    h1buf = ws + WS_H1;
  float*    s0r   = ws + WS_S0;
  unsigned* bar   = (unsigned*)(ws + WS_BAR);

  // zero recurrent-state buffers, the always-zero s1 output, and barrier counters
  hipMemsetAsync(h0buf, 0, 2 * HH * BB * sizeof(float), stream);
  hipMemsetAsync(h1buf, 0, 2 * HH * BB * sizeof(float), stream);
  hipMemsetAsync(out + SOFF + BB * HH, 0, BB * HH * sizeof(float), stream);
  hipMemsetAsync(bar, 0, 1024 * sizeof(unsigned), stream);

  transpose_x<<<dim3(T * 4), dim3(256), 0, stream>>>(x, xT);
  pack_w<<<dim3(II * 512 / 256), dim3(256), 0, stream>>>(Wx0, Wx0p, II);
  pack_w<<<dim3(HH * 512 / 256), dim3(256), 0, stream>>>(Wh0, Wh0p, HH);
  pack_w<<<dim3(HH * 512 / 256), dim3(256), 0, stream>>>(Wx1, Wx1p, HH);
  pack_w<<<dim3(HH * 512 / 256), dim3(256), 0, stream>>>(Wh1, Wh1p, HH);
  pack_bias<<<dim3(16), dim3(256), 0, stream>>>(bh0, bh1, bh0pf, bh1pf);

  aslstm_main<<<dim3(512), dim3(256), 0, stream>>>(
      xT, Wx0p, Wh0p, Wx1p, Wh1p, bh0p, bh1p,
      u0r, u1r, h0buf, h1buf, s0r, out, bar);
}